// Round 8
// baseline (286.664 us; speedup 1.0000x reference)
//
#include <hip/hip_runtime.h>
#include <hip/hip_bf16.h>
#include <math.h>

// Problem constants
#define NHEADS 16
#define HDIM   64
#define SEQT   2048
#define NBATCH 4
#define DMODEL 1024
#define MROWS  (NBATCH * SEQT)   // 8192

typedef __bf16 bf16;
typedef bf16  bf16x8 __attribute__((ext_vector_type(8)));
typedef float f32x4  __attribute__((ext_vector_type(4)));
typedef float f32x16 __attribute__((ext_vector_type(16)));
typedef unsigned int u32x4 __attribute__((ext_vector_type(4)));

#define MFMA_BF16(a, b, c) __builtin_amdgcn_mfma_f32_16x16x32_bf16((a), (b), (c), 0, 0, 0)
#define MFMA32(a, b, c)    __builtin_amdgcn_mfma_f32_32x32x16_bf16((a), (b), (c), 0, 0, 0)
#define Z16 {0.f,0.f,0.f,0.f,0.f,0.f,0.f,0.f,0.f,0.f,0.f,0.f,0.f,0.f,0.f,0.f}
#define LOG2E 1.44269504f

__device__ __forceinline__ void gload_lds16(const void* g, void* l) {
  __builtin_amdgcn_global_load_lds((const __attribute__((address_space(1))) void*)g,
                                   (__attribute__((address_space(3))) void*)l, 16, 0, 0);
}

__device__ __forceinline__ unsigned cvtpk_bf16(float lo, float hi) {
  unsigned r;
  asm("v_cvt_pk_bf16_f32 %0, %1, %2" : "=v"(r) : "v"(lo), "v"(hi));
  return r;
}
__device__ __forceinline__ void plswap(unsigned& a, unsigned& b) {
  asm volatile("v_permlane32_swap_b32 %0, %1" : "+v"(a), "+v"(b));
}
__device__ __forceinline__ float exp2v(float x) {     // 2^x via v_exp_f32
  float r;
  asm("v_exp_f32 %0, %1" : "=v"(r) : "v"(x));
  return r;
}

// ---------------- conversion / transpose pre-passes ----------------

__global__ __launch_bounds__(256) void k_cvt_f32_bf16(const float* __restrict__ in,
                                                      bf16* __restrict__ out, int n8) {
  int i = blockIdx.x * blockDim.x + threadIdx.x;
  if (i >= n8) return;
  const float4* in4 = (const float4*)in;
  float4 a = in4[(size_t)i * 2], b = in4[(size_t)i * 2 + 1];
  bf16x8 v;
  v[0] = (bf16)a.x; v[1] = (bf16)a.y; v[2] = (bf16)a.z; v[3] = (bf16)a.w;
  v[4] = (bf16)b.x; v[5] = (bf16)b.y; v[6] = (bf16)b.z; v[7] = (bf16)b.w;
  *(bf16x8*)(out + (size_t)i * 8) = v;
}

__global__ __launch_bounds__(256) void k_transpose_f32_bf16(const float* __restrict__ in,
                                                            bf16* __restrict__ out,
                                                            int R, int C) {
  int nct = C >> 6;
  int rt = blockIdx.x / nct, ct = blockIdx.x % nct;
  __shared__ float tile[64][65];
  int tid = threadIdx.x;
#pragma unroll
  for (int i = 0; i < 16; i++) {
    int e = i * 256 + tid, r = e >> 6, c = e & 63;
    tile[r][c] = in[(size_t)(rt * 64 + r) * C + ct * 64 + c];
  }
  __syncthreads();
#pragma unroll
  for (int i = 0; i < 16; i++) {
    int e = i * 256 + tid, r = e >> 6, c = e & 63;
    out[(size_t)(ct * 64 + r) * R + rt * 64 + c] = (bf16)tile[c][r];
  }
}

__global__ __launch_bounds__(256) void k_transpose_v(const bf16* __restrict__ v,
                                                     bf16* __restrict__ vt) {
  int tt = blockIdx.x & 31;     // T/64 = 32
  int bh = blockIdx.x >> 5;
  __shared__ bf16 tile[64][65];
  int tid = threadIdx.x;
  const bf16* src = v + (size_t)bh * SEQT * 64 + (size_t)tt * 64 * 64;
#pragma unroll
  for (int i = 0; i < 16; i++) {
    int e = i * 256 + tid, r = e >> 6, c = e & 63;
    tile[r][c] = src[r * 64 + c];
  }
  __syncthreads();
  bf16* dst = vt + (size_t)bh * 64 * SEQT + tt * 64;
#pragma unroll
  for (int i = 0; i < 16; i++) {
    int e = i * 256 + tid, r = e >> 6, c = e & 63;   // r = d, c = t-within-tile
    dst[(size_t)r * SEQT + c] = tile[c][r];
  }
}

// ---------------- m97-structure 128x128 GEMM core (BK=32) ----------------
// (reverted to the R3-measured version: no setprio, no XCD swizzle — both
// regressed ~10 us total in R7, consistent with T5/T1 priors on 2-phase
// L3-fit GEMMs)

__device__ __forceinline__ void gemm128_core(const bf16* __restrict__ A,
                                             const bf16* __restrict__ Bt,
                                             int K, int bm, int bn, char* smem,
                                             f32x4 (&acc)[4][4]) {
  int tid = threadIdx.x, lane = tid & 63, w = tid >> 6;
  int l15 = lane & 15, g = lane >> 4;
  int wrow = (w >> 1) * 64, wcol = (w & 1) * 64;
  char* As = smem;
  char* Bs = smem + 8192;
  const char* Ag = (const char*)(A + (size_t)bm * 128 * K);
  const char* Bg = (const char*)(Bt + (size_t)bn * 128 * K);
  const int rowB = K * 2;
  int srow = w * 16 + (lane >> 2);
  int scol = (lane & 3) * 16;

  for (int kt = 0; kt < K / 32; kt++) {
#pragma unroll
    for (int is = 0; is < 2; is++) {
      int row = is * 64 + srow;
      gload_lds16(Ag + (size_t)row * rowB + kt * 64 + scol, As + is * 4096 + w * 1024);
      gload_lds16(Bg + (size_t)row * rowB + kt * 64 + scol, Bs + is * 4096 + w * 1024);
    }
    __syncthreads();
    bf16x8 af[4], bfr[4];
#pragma unroll
    for (int i = 0; i < 4; i++)
      af[i] = *(const bf16x8*)&As[(wrow + i * 16 + l15) * 64 + g * 16];
#pragma unroll
    for (int j = 0; j < 4; j++)
      bfr[j] = *(const bf16x8*)&Bs[(wcol + j * 16 + l15) * 64 + g * 16];
#pragma unroll
    for (int i = 0; i < 4; i++)
#pragma unroll
      for (int j = 0; j < 4; j++)
        acc[i][j] = MFMA_BF16(af[i], bfr[j], acc[i][j]);
    __syncthreads();
  }
}

__global__ __launch_bounds__(256) void k_gemm_qkv(const bf16* __restrict__ A,
                                                  const bf16* __restrict__ Bt,
                                                  const float* __restrict__ bias,
                                                  bf16* __restrict__ Qo,
                                                  bf16* __restrict__ Ko,
                                                  bf16* __restrict__ Vo) {
  const int K = DMODEL, NB = 24;
  int bm = blockIdx.x / NB, bn = blockIdx.x % NB;
  __shared__ __align__(16) char smem[16384];
  f32x4 acc[4][4] = {};
  gemm128_core(A, Bt, K, bm, bn, smem, acc);

  int tid = threadIdx.x, lane = tid & 63, w = tid >> 6;
  int l15 = lane & 15, g = lane >> 4;
  int wrow = (w >> 1) * 64, wcol = (w & 1) * 64;
  int rowbase = bm * 128 + wrow;
  int b = (bm * 128) >> 11;
#pragma unroll
  for (int j = 0; j < 4; j++) {
    int n = bn * 128 + wcol + j * 16 + l15;
    float bj = bias[n];
    int which = n >> 10;
    int nn = n & 1023;
    int head = nn >> 6, d = nn & 63;
    bf16* dst = (which == 0) ? Qo : (which == 1) ? Ko : Vo;
    size_t base = ((size_t)(b * NHEADS + head) * SEQT) * 64 + d;
#pragma unroll
    for (int i = 0; i < 4; i++) {
#pragma unroll
      for (int r = 0; r < 4; r++) {
        int row = rowbase + i * 16 + g * 4 + r;
        int t = row & (SEQT - 1);
        dst[base + (size_t)t * 64] = (bf16)(acc[i][j][r] + bj);
      }
    }
  }
}

__global__ __launch_bounds__(256) void k_gemm_out(const bf16* __restrict__ A,
                                                  const bf16* __restrict__ Bt,
                                                  const float* __restrict__ bias,
                                                  float* __restrict__ C) {
  const int K = DMODEL, NB = 8;
  int bm = blockIdx.x / NB, bn = blockIdx.x % NB;
  __shared__ __align__(16) char smem[16384];
  f32x4 acc[4][4] = {};
  gemm128_core(A, Bt, K, bm, bn, smem, acc);

  int tid = threadIdx.x, lane = tid & 63, w = tid >> 6;
  int l15 = lane & 15, g = lane >> 4;
  int wrow = (w >> 1) * 64, wcol = (w & 1) * 64;
#pragma unroll
  for (int j = 0; j < 4; j++) {
    int n = bn * 128 + wcol + j * 16 + l15;
    float bj = bias[n];
#pragma unroll
    for (int i = 0; i < 4; i++) {
#pragma unroll
      for (int r = 0; r < 4; r++) {
        int row = bm * 128 + wrow + i * 16 + g * 4 + r;
        C[(size_t)row * DMODEL + n] = acc[i][j][r] + bj;
      }
    }
  }
}

// ---------------- flash attention (causal), swapped-QK 32x32 -------------
// Q,K: [BH][T][64] bf16 ; VT: [BH][64][T] bf16 ; out attn_o: [B*T][1024] bf16.
// CAUSAL PAIRING for perfect balance: block (j0, bh) processes q-tile j0 AND
// q-tile 31-j0 sequentially -> every block does exactly (j0+1)+(32-j0) = 33
// KV tiles. Grid = 16*64 = 1024 blocks x 128 threads (2 waves), 4 blocks/CU
// all-resident, zero drain tail. Per-tile math identical to the R7-measured
// kernel (swapped-QK mfma32, in-register softmax, ones-MFMA row sums).

__global__ __launch_bounds__(128) void k_attn(const bf16* __restrict__ Q,
                                              const bf16* __restrict__ Kg,
                                              const bf16* __restrict__ VT,
                                              bf16* __restrict__ Oo) {
  int bh = blockIdx.x & 63;
  int j0 = blockIdx.x >> 6;             // 0..15 -> chunks {j0, 31-j0}
  int tid = threadIdx.x, lane = tid & 63, wv = tid >> 6;   // wv 0..1
  int l31 = lane & 31, hi = lane >> 5;
  __shared__ __align__(16) char smem[32768];   // K dbuf 2x8K | V dbuf 2x8K

  const bf16* Qbh = Q + (size_t)bh * SEQT * 64;
  const char* Kbyte = (const char*)(Kg + (size_t)bh * SEQT * 64);
  const char* Vbyte = (const char*)(VT + (size_t)bh * 64 * SEQT);

  // staging: 8 chunks of 2KB (4 K + 4 V); 128 threads x 16B each
  int pp[4], lgK[4]; size_t vOff[4];
#pragma unroll
  for (int c = 0; c < 4; c++) {
    int p = c * 2048 + tid * 16;
    int row = p >> 7;
    int lg = p ^ ((row & 7) << 4);
    pp[c] = p; lgK[c] = lg;
    vOff[c] = (size_t)row * (SEQT * 2) + (lg & 127);
  }

  // ones B-fragment for row-sum MFMA
  bf16x8 onesf;
#pragma unroll
  for (int e = 0; e < 8; e++) onesf[e] = (bf16)1.0f;

  int b = bh >> 4, hd = bh & 15;

#pragma unroll 1
  for (int ck = 0; ck < 2; ck++) {
    int qt = ck ? (31 - j0) : j0;       // this chunk's 64-row q-tile
    int qbase = qt * 64 + wv * 32;
    int ql = qbase + l31;               // this lane's q row

    // Q fragments (B-operand): lane l holds Q[ql][d = s*16 + hi*8 + e]
    bf16x8 qf[4];
#pragma unroll
    for (int s = 0; s < 4; s++) {
      bf16x8 v = *(const bf16x8*)(Qbh + (size_t)ql * 64 + s * 16 + hi * 8);
#pragma unroll
      for (int e = 0; e < 8; e++) v[e] = (bf16)((float)v[e] * 0.125f);
      qf[s] = v;
    }

    float m = -INFINITY;
    f32x16 o0 = Z16, o1 = Z16, lacc = Z16;

    if (ck) __syncthreads();            // all waves done reading prev chunk's buffers
    // prologue: stage tile 0 into buffer 0
#pragma unroll
    for (int c = 0; c < 4; c++) {
      gload_lds16(Kbyte + lgK[c], smem + pp[c]);
      gload_lds16(Vbyte + vOff[c], smem + 16384 + pp[c]);
    }

    int NT = qt + 1;
    for (int t = 0; t < NT; t++) {
      __syncthreads();                  // stage(t) landed; compute(t-1) done
      if (t + 1 < NT) {
        int nx = (t + 1) & 1;
        const char* kg = Kbyte + (size_t)(t + 1) * 8192;
        const char* vg = Vbyte + (size_t)(t + 1) * 128;
#pragma unroll
        for (int c = 0; c < 4; c++) {
          gload_lds16(kg + lgK[c], smem + nx * 8192 + pp[c]);
          gload_lds16(vg + vOff[c], smem + 16384 + nx * 8192 + pp[c]);
        }
      }
      const char* Ks = smem + (t & 1) * 8192;
      const char* Vs = smem + 16384 + (t & 1) * 8192;

      // ---- S^T halves: st[h] = K[32h..32h+31] @ Q^T ----
      f32x16 st[2];
      __builtin_amdgcn_s_setprio(1);
#pragma unroll
      for (int h = 0; h < 2; h++) {
        f32x16 acc = Z16;
#pragma unroll
        for (int s = 0; s < 4; s++) {
          int row = h * 32 + l31;
          bf16x8 kf = *(const bf16x8*)&Ks[(row * 128 + s * 32 + hi * 16) ^ ((l31 & 7) << 4)];
          acc = MFMA32(kf, qf[s], acc);
        }
        st[h] = acc;
      }
      __builtin_amdgcn_s_setprio(0);

      // ---- causal mask (last tile only) ----
      if (t == NT - 1) {
        int rel = ql - (t * 64 + 4 * hi);
#pragma unroll
        for (int r = 0; r < 16; r++) {
          const int R0 = (r & 3) + 8 * (r >> 2);
          if (R0 > rel) st[0][r] = -INFINITY;
          if (R0 > rel - 32) st[1][r] = -INFINITY;
        }
      }

      // ---- row max: 4 ILP chains + one cross shfl ----
      float m0 = -INFINITY, m1 = -INFINITY, m2 = -INFINITY, m3 = -INFINITY;
#pragma unroll
      for (int h = 0; h < 2; h++)
#pragma unroll
        for (int r = 0; r < 16; r += 4) {
          m0 = fmaxf(m0, st[h][r]);
          m1 = fmaxf(m1, st[h][r + 1]);
          m2 = fmaxf(m2, st[h][r + 2]);
          m3 = fmaxf(m3, st[h][r + 3]);
        }
      float mx = fmaxf(fmaxf(m0, m1), fmaxf(m2, m3));
      mx = fmaxf(mx, __shfl_xor(mx, 32));

      // ---- defer-max rescale (rare) ----
      if (__any(mx > m + 8.f)) {
        float mn = fmaxf(m, mx);
        float co = exp2v((m - mn) * LOG2E);
        m = mn;
#pragma unroll
        for (int r = 0; r < 16; r++) {
          const int R0 = (r & 3) + 8 * (r >> 2);
          float fac = __shfl(co, R0 + 4 * hi);
          o0[r] *= fac; o1[r] *= fac; lacc[r] *= fac;
        }
      }

      // ---- exp: p = 2^(s*log2e - m*log2e) ----
      float negmq = -m * LOG2E;
#pragma unroll
      for (int h = 0; h < 2; h++)
#pragma unroll
        for (int r = 0; r < 16; r++)
          st[h][r] = exp2v(fmaf(st[h][r], LOG2E, negmq));

      // ---- pack P -> A-frags, then PV + ones-sum ----
      __builtin_amdgcn_s_setprio(1);
#pragma unroll
      for (int h = 0; h < 2; h++) {
        unsigned pw[8];
#pragma unroll
        for (int i = 0; i < 8; i++) pw[i] = cvtpk_bf16(st[h][2 * i], st[h][2 * i + 1]);
        plswap(pw[0], pw[2]); plswap(pw[1], pw[3]);
        plswap(pw[4], pw[6]); plswap(pw[5], pw[7]);
        u32x4 f0 = {pw[0], pw[1], pw[2], pw[3]};
        u32x4 f1 = {pw[4], pw[5], pw[6], pw[7]};
        bf16x8 pa0 = __builtin_bit_cast(bf16x8, f0);   // kv slot 2h
        bf16x8 pa1 = __builtin_bit_cast(bf16x8, f1);   // kv slot 2h+1
        lacc = MFMA32(pa0, onesf, lacc);               // row sums, O-layout
        lacc = MFMA32(pa1, onesf, lacc);
        {
          int vrow = l31;
          bf16x8 bv0 = *(const bf16x8*)&Vs[(vrow * 128 + (2 * h) * 32 + hi * 16) ^ ((l31 & 7) << 4)];
          bf16x8 bv1 = *(const bf16x8*)&Vs[(vrow * 128 + (2 * h + 1) * 32 + hi * 16) ^ ((l31 & 7) << 4)];
          o0 = MFMA32(pa0, bv0, o0);
          o0 = MFMA32(pa1, bv1, o0);
        }
        {
          int vrow = 32 + l31;
          bf16x8 bv0 = *(const bf16x8*)&Vs[(vrow * 128 + (2 * h) * 32 + hi * 16) ^ ((l31 & 7) << 4)];
          bf16x8 bv1 = *(const bf16x8*)&Vs[(vrow * 128 + (2 * h + 1) * 32 + hi * 16) ^ ((l31 & 7) << 4)];
          o1 = MFMA32(pa0, bv0, o1);
          o1 = MFMA32(pa1, bv1, o1);
        }
      }
      __builtin_amdgcn_s_setprio(0);
    }

    // ---- normalize + write this chunk's rows [B*T][1024] bf16 ----
#pragma unroll
    for (int r = 0; r < 16; r++) {
      const int R0 = (r & 3) + 8 * (r >> 2);
      int qrow = qbase + R0 + 4 * hi;
      float inv = 1.f / lacc[r];
      size_t off = ((size_t)(b * SEQT + qrow)) * DMODEL + hd * 64;
      Oo[off + l31]      = (bf16)(o0[r] * inv);
      Oo[off + 32 + l31] = (bf16)(o1[r] * inv);
    }
  }
}

// ---------------- launcher ----------------

extern "C" void kernel_launch(void* const* d_in, const int* in_sizes, int n_in,
                              void* d_out, int out_size, void* d_ws, size_t ws_size,
                              hipStream_t stream) {
  const float* x     = (const float*)d_in[0];
  const float* w_qkv = (const float*)d_in[1];
  const float* b_qkv = (const float*)d_in[2];
  const float* w_out = (const float*)d_in[3];
  const float* b_out = (const float*)d_in[4];
  float* out = (float*)d_out;

  char* ws = (char*)d_ws;
  bf16* xb    = (bf16*)(ws);                        // 16 MiB (reused as attn_out)
  bf16* wqkvT = (bf16*)(ws + (16u << 20));          //  6 MiB
  bf16* woutT = (bf16*)(ws + (22u << 20));          //  2 MiB
  bf16* Qb    = (bf16*)(ws + (24u << 20));          // 16 MiB
  bf16* Kb    = (bf16*)(ws + (40u << 20));          // 16 MiB
  bf16* Vb    = (bf16*)(ws + (56u << 20));          // 16 MiB
  bf16* VTb   = (bf16*)(ws + (72u << 20));          // 16 MiB (total 88 MiB)
  bf16* attn_o = xb;                                // xb dead after QKV GEMM

  k_cvt_f32_bf16<<<(MROWS * DMODEL / 8 + 255) / 256, 256, 0, stream>>>(x, xb, MROWS * DMODEL / 8);
  k_transpose_f32_bf16<<<16 * 48, 256, 0, stream>>>(w_qkv, wqkvT, DMODEL, 3 * DMODEL);
  k_transpose_f32_bf16<<<16 * 16, 256, 0, stream>>>(w_out, woutT, DMODEL, DMODEL);
  k_gemm_qkv<<<64 * 24, 256, 0, stream>>>(xb, wqkvT, b_qkv, Qb, Kb, Vb);
  k_transpose_v<<<64 * 32, 256, 0, stream>>>(Vb, VTb);
  k_attn<<<16 * 64, 128, 0, stream>>>(Qb, Kb, VTb, attn_o);
  k_gemm_out<<<64 * 8, 256, 0, stream>>>(attn_o, woutT, b_out, out);
}

// Round 9
// 284.583 us; speedup vs baseline: 1.0073x; 1.0073x over previous
//
#include <hip/hip_runtime.h>
#include <hip/hip_bf16.h>
#include <math.h>

// Problem constants
#define NHEADS 16
#define HDIM   64
#define SEQT   2048
#define NBATCH 4
#define DMODEL 1024
#define MROWS  (NBATCH * SEQT)   // 8192

typedef __bf16 bf16;
typedef bf16  bf16x8 __attribute__((ext_vector_type(8)));
typedef float f32x4  __attribute__((ext_vector_type(4)));
typedef float f32x16 __attribute__((ext_vector_type(16)));
typedef unsigned int u32x4 __attribute__((ext_vector_type(4)));

#define MFMA_BF16(a, b, c) __builtin_amdgcn_mfma_f32_16x16x32_bf16((a), (b), (c), 0, 0, 0)
#define MFMA32(a, b, c)    __builtin_amdgcn_mfma_f32_32x32x16_bf16((a), (b), (c), 0, 0, 0)
#define Z16 {0.f,0.f,0.f,0.f,0.f,0.f,0.f,0.f,0.f,0.f,0.f,0.f,0.f,0.f,0.f,0.f}
#define LOG2E 1.44269504f

__device__ __forceinline__ void gload_lds16(const void* g, void* l) {
  __builtin_amdgcn_global_load_lds((const __attribute__((address_space(1))) void*)g,
                                   (__attribute__((address_space(3))) void*)l, 16, 0, 0);
}

__device__ __forceinline__ unsigned cvtpk_bf16(float lo, float hi) {
  unsigned r;
  asm("v_cvt_pk_bf16_f32 %0, %1, %2" : "=v"(r) : "v"(lo), "v"(hi));
  return r;
}
__device__ __forceinline__ void plswap(unsigned& a, unsigned& b) {
  asm volatile("v_permlane32_swap_b32 %0, %1" : "+v"(a), "+v"(b));
}
__device__ __forceinline__ float exp2v(float x) {     // 2^x via v_exp_f32
  float r;
  asm("v_exp_f32 %0, %1" : "=v"(r) : "v"(x));
  return r;
}

// ---------------- conversion / transpose pre-passes ----------------

__global__ __launch_bounds__(256) void k_cvt_f32_bf16(const float* __restrict__ in,
                                                      bf16* __restrict__ out, int n8) {
  int i = blockIdx.x * blockDim.x + threadIdx.x;
  if (i >= n8) return;
  const float4* in4 = (const float4*)in;
  float4 a = in4[(size_t)i * 2], b = in4[(size_t)i * 2 + 1];
  bf16x8 v;
  v[0] = (bf16)a.x; v[1] = (bf16)a.y; v[2] = (bf16)a.z; v[3] = (bf16)a.w;
  v[4] = (bf16)b.x; v[5] = (bf16)b.y; v[6] = (bf16)b.z; v[7] = (bf16)b.w;
  *(bf16x8*)(out + (size_t)i * 8) = v;
}

__global__ __launch_bounds__(256) void k_transpose_f32_bf16(const float* __restrict__ in,
                                                            bf16* __restrict__ out,
                                                            int R, int C) {
  int nct = C >> 6;
  int rt = blockIdx.x / nct, ct = blockIdx.x % nct;
  __shared__ float tile[64][65];
  int tid = threadIdx.x;
#pragma unroll
  for (int i = 0; i < 16; i++) {
    int e = i * 256 + tid, r = e >> 6, c = e & 63;
    tile[r][c] = in[(size_t)(rt * 64 + r) * C + ct * 64 + c];
  }
  __syncthreads();
#pragma unroll
  for (int i = 0; i < 16; i++) {
    int e = i * 256 + tid, r = e >> 6, c = e & 63;
    out[(size_t)(ct * 64 + r) * R + rt * 64 + c] = (bf16)tile[c][r];
  }
}

__global__ __launch_bounds__(256) void k_transpose_v(const bf16* __restrict__ v,
                                                     bf16* __restrict__ vt) {
  int tt = blockIdx.x & 31;     // T/64 = 32
  int bh = blockIdx.x >> 5;
  __shared__ bf16 tile[64][65];
  int tid = threadIdx.x;
  const bf16* src = v + (size_t)bh * SEQT * 64 + (size_t)tt * 64 * 64;
#pragma unroll
  for (int i = 0; i < 16; i++) {
    int e = i * 256 + tid, r = e >> 6, c = e & 63;
    tile[r][c] = src[r * 64 + c];
  }
  __syncthreads();
  bf16* dst = vt + (size_t)bh * 64 * SEQT + tt * 64;
#pragma unroll
  for (int i = 0; i < 16; i++) {
    int e = i * 256 + tid, r = e >> 6, c = e & 63;   // r = d, c = t-within-tile
    dst[(size_t)r * SEQT + c] = tile[c][r];
  }
}

// ---------------- m97-structure 128x128 GEMM core (BK=32) ----------------
// (R3-measured version: no setprio, no XCD swizzle)

__device__ __forceinline__ void gemm128_core(const bf16* __restrict__ A,
                                             const bf16* __restrict__ Bt,
                                             int K, int bm, int bn, char* smem,
                                             f32x4 (&acc)[4][4]) {
  int tid = threadIdx.x, lane = tid & 63, w = tid >> 6;
  int l15 = lane & 15, g = lane >> 4;
  int wrow = (w >> 1) * 64, wcol = (w & 1) * 64;
  char* As = smem;
  char* Bs = smem + 8192;
  const char* Ag = (const char*)(A + (size_t)bm * 128 * K);
  const char* Bg = (const char*)(Bt + (size_t)bn * 128 * K);
  const int rowB = K * 2;
  int srow = w * 16 + (lane >> 2);
  int scol = (lane & 3) * 16;

  for (int kt = 0; kt < K / 32; kt++) {
#pragma unroll
    for (int is = 0; is < 2; is++) {
      int row = is * 64 + srow;
      gload_lds16(Ag + (size_t)row * rowB + kt * 64 + scol, As + is * 4096 + w * 1024);
      gload_lds16(Bg + (size_t)row * rowB + kt * 64 + scol, Bs + is * 4096 + w * 1024);
    }
    __syncthreads();
    bf16x8 af[4], bfr[4];
#pragma unroll
    for (int i = 0; i < 4; i++)
      af[i] = *(const bf16x8*)&As[(wrow + i * 16 + l15) * 64 + g * 16];
#pragma unroll
    for (int j = 0; j < 4; j++)
      bfr[j] = *(const bf16x8*)&Bs[(wcol + j * 16 + l15) * 64 + g * 16];
#pragma unroll
    for (int i = 0; i < 4; i++)
#pragma unroll
      for (int j = 0; j < 4; j++)
        acc[i][j] = MFMA_BF16(af[i], bfr[j], acc[i][j]);
    __syncthreads();
  }
}

__global__ __launch_bounds__(256) void k_gemm_qkv(const bf16* __restrict__ A,
                                                  const bf16* __restrict__ Bt,
                                                  const float* __restrict__ bias,
                                                  bf16* __restrict__ Qo,
                                                  bf16* __restrict__ Ko,
                                                  bf16* __restrict__ Vo) {
  const int K = DMODEL, NB = 24;
  int bm = blockIdx.x / NB, bn = blockIdx.x % NB;
  __shared__ __align__(16) char smem[16384];
  f32x4 acc[4][4] = {};
  gemm128_core(A, Bt, K, bm, bn, smem, acc);

  int tid = threadIdx.x, lane = tid & 63, w = tid >> 6;
  int l15 = lane & 15, g = lane >> 4;
  int wrow = (w >> 1) * 64, wcol = (w & 1) * 64;
  int rowbase = bm * 128 + wrow;
  int b = (bm * 128) >> 11;
#pragma unroll
  for (int j = 0; j < 4; j++) {
    int n = bn * 128 + wcol + j * 16 + l15;
    float bj = bias[n];
    int which = n >> 10;
    int nn = n & 1023;
    int head = nn >> 6, d = nn & 63;
    bf16* dst = (which == 0) ? Qo : (which == 1) ? Ko : Vo;
    size_t base = ((size_t)(b * NHEADS + head) * SEQT) * 64 + d;
#pragma unroll
    for (int i = 0; i < 4; i++) {
#pragma unroll
      for (int r = 0; r < 4; r++) {
        int row = rowbase + i * 16 + g * 4 + r;
        int t = row & (SEQT - 1);
        dst[base + (size_t)t * 64] = (bf16)(acc[i][j][r] + bj);
      }
    }
  }
}

__global__ __launch_bounds__(256) void k_gemm_out(const bf16* __restrict__ A,
                                                  const bf16* __restrict__ Bt,
                                                  const float* __restrict__ bias,
                                                  float* __restrict__ C) {
  const int K = DMODEL, NB = 8;
  int bm = blockIdx.x / NB, bn = blockIdx.x % NB;
  __shared__ __align__(16) char smem[16384];
  f32x4 acc[4][4] = {};
  gemm128_core(A, Bt, K, bm, bn, smem, acc);

  int tid = threadIdx.x, lane = tid & 63, w = tid >> 6;
  int l15 = lane & 15, g = lane >> 4;
  int wrow = (w >> 1) * 64, wcol = (w & 1) * 64;
#pragma unroll
  for (int j = 0; j < 4; j++) {
    int n = bn * 128 + wcol + j * 16 + l15;
    float bj = bias[n];
#pragma unroll
    for (int i = 0; i < 4; i++) {
#pragma unroll
      for (int r = 0; r < 4; r++) {
        int row = bm * 128 + wrow + i * 16 + g * 4 + r;
        C[(size_t)row * DMODEL + n] = acc[i][j][r] + bj;
      }
    }
  }
}

// ---------------- flash attention (causal), swapped-QK 32x32 -------------
// R7 grid (2048 blocks x 128 thr, longest-first, 1 q-tile/block) + V-DIRECT:
// V is NOT staged in LDS (L3-resident, catalog #7); bv fragments load from
// global VT at the exact per-lane fragment address, issued before QK^T so
// ~600cyc of compute hides their latency. LDS = K dbuf only (16KB) ->
// LDS cap 10 blocks/CU; launch_bounds(128,3) caps VGPR for >=12 waves/CU.

__global__ __launch_bounds__(128, 3) void k_attn(const bf16* __restrict__ Q,
                                                 const bf16* __restrict__ Kg,
                                                 const bf16* __restrict__ VT,
                                                 bf16* __restrict__ Oo) {
  int bh = blockIdx.x & 63;
  int qi = 31 - (blockIdx.x >> 6);      // 64-row q-tile, longest-first, 0..31
  int tid = threadIdx.x, lane = tid & 63, wv = tid >> 6;   // wv 0..1
  int l31 = lane & 31, hi = lane >> 5;
  __shared__ __align__(16) char smem[16384];   // K dbuf 2x8K (V not staged)

  const bf16* Qbh = Q + (size_t)bh * SEQT * 64;
  const char* Kbyte = (const char*)(Kg + (size_t)bh * SEQT * 64);
  const char* Vbyte = (const char*)(VT + (size_t)bh * 64 * SEQT);
  int qbase = qi * 64 + wv * 32;
  int ql = qbase + l31;                 // this lane's q row

  // K staging: 4 chunks of 2KB; 128 threads x 16B each
  int pp[4], lgK[4];
#pragma unroll
  for (int c = 0; c < 4; c++) {
    int p = c * 2048 + tid * 16;
    int row = p >> 7;
    pp[c] = p; lgK[c] = p ^ ((row & 7) << 4);
  }

  // V fragment lane bases: rows l31 (for o0) and 32+l31 (for o1), cols hi*16
  const char* vb0 = Vbyte + (size_t)l31 * (SEQT * 2) + hi * 16;
  const char* vb1 = Vbyte + (size_t)(32 + l31) * (SEQT * 2) + hi * 16;

  // Q fragments (B-operand): lane l holds Q[ql][d = s*16 + hi*8 + e]
  bf16x8 qf[4];
#pragma unroll
  for (int s = 0; s < 4; s++) {
    bf16x8 v = *(const bf16x8*)(Qbh + (size_t)ql * 64 + s * 16 + hi * 8);
#pragma unroll
    for (int e = 0; e < 8; e++) v[e] = (bf16)((float)v[e] * 0.125f);
    qf[s] = v;
  }

  // ones B-fragment for row-sum MFMA
  bf16x8 onesf;
#pragma unroll
  for (int e = 0; e < 8; e++) onesf[e] = (bf16)1.0f;

  float m = -INFINITY;
  f32x16 o0 = Z16, o1 = Z16, lacc = Z16;

  // prologue: stage K tile 0 into buffer 0
#pragma unroll
  for (int c = 0; c < 4; c++)
    gload_lds16(Kbyte + lgK[c], smem + pp[c]);

  int NT = qi + 1;
  for (int t = 0; t < NT; t++) {
    __syncthreads();                    // K stage(t) landed; compute(t-1) done
    if (t + 1 < NT) {
      int nx = (t + 1) & 1;
      const char* kg = Kbyte + (size_t)(t + 1) * 8192;
#pragma unroll
      for (int c = 0; c < 4; c++)
        gload_lds16(kg + lgK[c], smem + nx * 8192 + pp[c]);
    }
    const char* Ks = smem + (t & 1) * 8192;

    // ---- V fragments for tile t: direct global loads, issued early so the
    //      QK^T + softmax below hides their latency ----
    const char* v0t = vb0 + (size_t)t * 128;
    const char* v1t = vb1 + (size_t)t * 128;
    bf16x8 bv0[4], bv1[4];
#pragma unroll
    for (int ks = 0; ks < 4; ks++) {
      bv0[ks] = *(const bf16x8*)(v0t + ks * 32);
      bv1[ks] = *(const bf16x8*)(v1t + ks * 32);
    }

    // ---- S^T halves: st[h] = K[32h..32h+31] @ Q^T ----
    f32x16 st[2];
    __builtin_amdgcn_s_setprio(1);
#pragma unroll
    for (int h = 0; h < 2; h++) {
      f32x16 acc = Z16;
#pragma unroll
      for (int s = 0; s < 4; s++) {
        int row = h * 32 + l31;
        bf16x8 kf = *(const bf16x8*)&Ks[(row * 128 + s * 32 + hi * 16) ^ ((l31 & 7) << 4)];
        acc = MFMA32(kf, qf[s], acc);
      }
      st[h] = acc;
    }
    __builtin_amdgcn_s_setprio(0);

    // ---- causal mask (last tile only) ----
    if (t == NT - 1) {
      int rel = ql - (t * 64 + 4 * hi);
#pragma unroll
      for (int r = 0; r < 16; r++) {
        const int R0 = (r & 3) + 8 * (r >> 2);
        if (R0 > rel) st[0][r] = -INFINITY;
        if (R0 > rel - 32) st[1][r] = -INFINITY;
      }
    }

    // ---- row max: 4 ILP chains + one cross shfl ----
    float m0 = -INFINITY, m1 = -INFINITY, m2 = -INFINITY, m3 = -INFINITY;
#pragma unroll
    for (int h = 0; h < 2; h++)
#pragma unroll
      for (int r = 0; r < 16; r += 4) {
        m0 = fmaxf(m0, st[h][r]);
        m1 = fmaxf(m1, st[h][r + 1]);
        m2 = fmaxf(m2, st[h][r + 2]);
        m3 = fmaxf(m3, st[h][r + 3]);
      }
    float mx = fmaxf(fmaxf(m0, m1), fmaxf(m2, m3));
    mx = fmaxf(mx, __shfl_xor(mx, 32));

    // ---- defer-max rescale (rare) ----
    if (__any(mx > m + 8.f)) {
      float mn = fmaxf(m, mx);
      float co = exp2v((m - mn) * LOG2E);
      m = mn;
#pragma unroll
      for (int r = 0; r < 16; r++) {
        const int R0 = (r & 3) + 8 * (r >> 2);
        float fac = __shfl(co, R0 + 4 * hi);
        o0[r] *= fac; o1[r] *= fac; lacc[r] *= fac;
      }
    }

    // ---- exp: p = 2^(s*log2e - m*log2e) ----
    float negmq = -m * LOG2E;
#pragma unroll
    for (int h = 0; h < 2; h++)
#pragma unroll
      for (int r = 0; r < 16; r++)
        st[h][r] = exp2v(fmaf(st[h][r], LOG2E, negmq));

    // ---- pack P -> A-frags, then PV + ones-sum ----
    __builtin_amdgcn_s_setprio(1);
#pragma unroll
    for (int h = 0; h < 2; h++) {
      unsigned pw[8];
#pragma unroll
      for (int i = 0; i < 8; i++) pw[i] = cvtpk_bf16(st[h][2 * i], st[h][2 * i + 1]);
      plswap(pw[0], pw[2]); plswap(pw[1], pw[3]);
      plswap(pw[4], pw[6]); plswap(pw[5], pw[7]);
      u32x4 f0 = {pw[0], pw[1], pw[2], pw[3]};
      u32x4 f1 = {pw[4], pw[5], pw[6], pw[7]};
      bf16x8 pa0 = __builtin_bit_cast(bf16x8, f0);   // kv slot 2h
      bf16x8 pa1 = __builtin_bit_cast(bf16x8, f1);   // kv slot 2h+1
      lacc = MFMA32(pa0, onesf, lacc);               // row sums, O-layout
      lacc = MFMA32(pa1, onesf, lacc);
      o0 = MFMA32(pa0, bv0[2 * h], o0);
      o0 = MFMA32(pa1, bv0[2 * h + 1], o0);
      o1 = MFMA32(pa0, bv1[2 * h], o1);
      o1 = MFMA32(pa1, bv1[2 * h + 1], o1);
    }
    __builtin_amdgcn_s_setprio(0);
  }

  // ---- normalize + write attn_out [B*T][1024] bf16 ----
  int b = bh >> 4, hd = bh & 15;
#pragma unroll
  for (int r = 0; r < 16; r++) {
    const int R0 = (r & 3) + 8 * (r >> 2);
    int qrow = qbase + R0 + 4 * hi;
    float inv = 1.f / lacc[r];
    size_t off = ((size_t)(b * SEQT + qrow)) * DMODEL + hd * 64;
    Oo[off + l31]      = (bf16)(o0[r] * inv);
    Oo[off + 32 + l31] = (bf16)(o1[r] * inv);
  }
}

// ---------------- launcher ----------------

extern "C" void kernel_launch(void* const* d_in, const int* in_sizes, int n_in,
                              void* d_out, int out_size, void* d_ws, size_t ws_size,
                              hipStream_t stream) {
  const float* x     = (const float*)d_in[0];
  const float* w_qkv = (const float*)d_in[1];
  const float* b_qkv = (const float*)d_in[2];
  const float* w_out = (const float*)d_in[3];
  const float* b_out = (const float*)d_in[4];
  float* out = (float*)d_out;

  char* ws = (char*)d_ws;
  bf16* xb    = (bf16*)(ws);                        // 16 MiB (reused as attn_out)
  bf16* wqkvT = (bf16*)(ws + (16u << 20));          //  6 MiB
  bf16* woutT = (bf16*)(ws + (22u << 20));          //  2 MiB
  bf16* Qb    = (bf16*)(ws + (24u << 20));          // 16 MiB
  bf16* Kb    = (bf16*)(ws + (40u << 20));          // 16 MiB
  bf16* Vb    = (bf16*)(ws + (56u << 20));          // 16 MiB
  bf16* VTb   = (bf16*)(ws + (72u << 20));          // 16 MiB (total 88 MiB)
  bf16* attn_o = xb;                                // xb dead after QKV GEMM

  k_cvt_f32_bf16<<<(MROWS * DMODEL / 8 + 255) / 256, 256, 0, stream>>>(x, xb, MROWS * DMODEL / 8);
  k_transpose_f32_bf16<<<16 * 48, 256, 0, stream>>>(w_qkv, wqkvT, DMODEL, 3 * DMODEL);
  k_transpose_f32_bf16<<<16 * 16, 256, 0, stream>>>(w_out, woutT, DMODEL, DMODEL);
  k_gemm_qkv<<<64 * 24, 256, 0, stream>>>(xb, wqkvT, b_qkv, Qb, Kb, Vb);
  k_transpose_v<<<64 * 32, 256, 0, stream>>>(Vb, VTb);
  k_attn<<<32 * 64, 128, 0, stream>>>(Qb, Kb, VTb, attn_o);
  k_gemm_out<<<64 * 8, 256, 0, stream>>>(attn_o, woutT, b_out, out);
}

// Round 10
// 267.626 us; speedup vs baseline: 1.0711x; 1.0634x over previous
//
#include <hip/hip_runtime.h>
#include <hip/hip_bf16.h>
#include <math.h>

// Problem constants
#define NHEADS 16
#define HDIM   64
#define SEQT   2048
#define NBATCH 4
#define DMODEL 1024
#define MROWS  (NBATCH * SEQT)   // 8192

typedef __bf16 bf16;
typedef bf16  bf16x8 __attribute__((ext_vector_type(8)));
typedef float f32x4  __attribute__((ext_vector_type(4)));
typedef float f32x16 __attribute__((ext_vector_type(16)));
typedef unsigned int u32x4 __attribute__((ext_vector_type(4)));

#define MFMA_BF16(a, b, c) __builtin_amdgcn_mfma_f32_16x16x32_bf16((a), (b), (c), 0, 0, 0)
#define MFMA32(a, b, c)    __builtin_amdgcn_mfma_f32_32x32x16_bf16((a), (b), (c), 0, 0, 0)
#define Z16 {0.f,0.f,0.f,0.f,0.f,0.f,0.f,0.f,0.f,0.f,0.f,0.f,0.f,0.f,0.f,0.f}
#define LOG2E 1.44269504f

__device__ __forceinline__ void gload_lds16(const void* g, void* l) {
  __builtin_amdgcn_global_load_lds((const __attribute__((address_space(1))) void*)g,
                                   (__attribute__((address_space(3))) void*)l, 16, 0, 0);
}

__device__ __forceinline__ unsigned cvtpk_bf16(float lo, float hi) {
  unsigned r;
  asm("v_cvt_pk_bf16_f32 %0, %1, %2" : "=v"(r) : "v"(lo), "v"(hi));
  return r;
}
__device__ __forceinline__ void plswap(unsigned& a, unsigned& b) {
  asm volatile("v_permlane32_swap_b32 %0, %1" : "+v"(a), "+v"(b));
}
__device__ __forceinline__ float exp2v(float x) {     // 2^x via v_exp_f32
  float r;
  asm("v_exp_f32 %0, %1" : "=v"(r) : "v"(x));
  return r;
}

// ---------------- conversion / transpose pre-passes ----------------

__global__ __launch_bounds__(256) void k_cvt_f32_bf16(const float* __restrict__ in,
                                                      bf16* __restrict__ out, int n8) {
  int i = blockIdx.x * blockDim.x + threadIdx.x;
  if (i >= n8) return;
  const float4* in4 = (const float4*)in;
  float4 a = in4[(size_t)i * 2], b = in4[(size_t)i * 2 + 1];
  bf16x8 v;
  v[0] = (bf16)a.x; v[1] = (bf16)a.y; v[2] = (bf16)a.z; v[3] = (bf16)a.w;
  v[4] = (bf16)b.x; v[5] = (bf16)b.y; v[6] = (bf16)b.z; v[7] = (bf16)b.w;
  *(bf16x8*)(out + (size_t)i * 8) = v;
}

__global__ __launch_bounds__(256) void k_transpose_f32_bf16(const float* __restrict__ in,
                                                            bf16* __restrict__ out,
                                                            int R, int C) {
  int nct = C >> 6;
  int rt = blockIdx.x / nct, ct = blockIdx.x % nct;
  __shared__ float tile[64][65];
  int tid = threadIdx.x;
#pragma unroll
  for (int i = 0; i < 16; i++) {
    int e = i * 256 + tid, r = e >> 6, c = e & 63;
    tile[r][c] = in[(size_t)(rt * 64 + r) * C + ct * 64 + c];
  }
  __syncthreads();
#pragma unroll
  for (int i = 0; i < 16; i++) {
    int e = i * 256 + tid, r = e >> 6, c = e & 63;
    out[(size_t)(ct * 64 + r) * R + rt * 64 + c] = (bf16)tile[c][r];
  }
}

__global__ __launch_bounds__(256) void k_transpose_v(const bf16* __restrict__ v,
                                                     bf16* __restrict__ vt) {
  int tt = blockIdx.x & 31;     // T/64 = 32
  int bh = blockIdx.x >> 5;
  __shared__ bf16 tile[64][65];
  int tid = threadIdx.x;
  const bf16* src = v + (size_t)bh * SEQT * 64 + (size_t)tt * 64 * 64;
#pragma unroll
  for (int i = 0; i < 16; i++) {
    int e = i * 256 + tid, r = e >> 6, c = e & 63;
    tile[r][c] = src[r * 64 + c];
  }
  __syncthreads();
  bf16* dst = vt + (size_t)bh * 64 * SEQT + tt * 64;
#pragma unroll
  for (int i = 0; i < 16; i++) {
    int e = i * 256 + tid, r = e >> 6, c = e & 63;   // r = d, c = t-within-tile
    dst[(size_t)r * SEQT + c] = tile[c][r];
  }
}

// ---- 4-buffer counted-vmcnt GEMM (T3/T4): BM=128 BN=256 BK=32, 512 thr ----
// A [M][1024] bf16 row-major, Bt [N][1024] bf16 row-major. 8 waves (2Mx4N),
// each 64x64 output (acc[4][4]). LDS: 4 buffers x (A 8KB + B 16KB) = 96KB.
// Pipeline: prefetch depth 3, s_waitcnt vmcnt(9) steady (NEVER 0 in-loop),
// raw s_barrier + manual lgkmcnt (no __syncthreads = no vmcnt(0) drain).
// Race safety: stage(kt+3) writes buf[(kt-1)&3], all reads of which completed
// before barrier#2 of step kt-1; landing gated by vmcnt(9) at step kt+3.
// Swizzle involution (col ^ ((row&3)<<4)) applied on BOTH stage-src and read.

__device__ __forceinline__ void stage_tile(const char* Ag, const char* Bg,
                                           char* buf, int kt, int tid) {
  int pa = tid * 16;                          // A region: 8KB, 1 load/thread
  int ra = pa >> 6, ca = pa & 63;
  gload_lds16(Ag + (size_t)ra * 2048 + kt * 64 + (ca ^ ((ra & 3) << 4)), buf + pa);
  int pb0 = tid * 16;                         // B region: 16KB, 2 loads/thread
  int rb0 = pb0 >> 6, cb0 = pb0 & 63;
  gload_lds16(Bg + (size_t)rb0 * 2048 + kt * 64 + (cb0 ^ ((rb0 & 3) << 4)),
              buf + 8192 + pb0);
  int pb1 = pb0 + 8192;
  int rb1 = pb1 >> 6, cb1 = pb1 & 63;
  gload_lds16(Bg + (size_t)rb1 * 2048 + kt * 64 + (cb1 ^ ((rb1 & 3) << 4)),
              buf + 8192 + pb1);
}

__device__ __forceinline__ void gemm_core512(const bf16* __restrict__ A,
                                             const bf16* __restrict__ Bt,
                                             int bm, int bn, char* smem,
                                             f32x4 (&acc)[4][4]) {
  const int NK = 32;                          // K=1024 / BK=32
  int tid = threadIdx.x, lane = tid & 63;
  int l15 = lane & 15, g = lane >> 4;
  int wid = tid >> 6, wr = wid >> 2, wc = wid & 3;
  const char* Ag = (const char*)(A + (size_t)bm * 128 * 1024);
  const char* Bg = (const char*)(Bt + (size_t)bn * 256 * 1024);

  // frag byte offsets within a buffer (read side of the swizzle involution)
  int aoff[4], boff[4];
#pragma unroll
  for (int i = 0; i < 4; i++) {
    int row = wr * 64 + i * 16 + l15;
    aoff[i] = row * 64 + ((g * 16) ^ ((row & 3) << 4));
  }
#pragma unroll
  for (int j = 0; j < 4; j++) {
    int row = wc * 64 + j * 16 + l15;
    boff[j] = 8192 + row * 64 + ((g * 16) ^ ((row & 3) << 4));
  }

  // prologue: stage tiles 0,1,2
  stage_tile(Ag, Bg, smem + 0 * 24576, 0, tid);
  stage_tile(Ag, Bg, smem + 1 * 24576, 1, tid);
  stage_tile(Ag, Bg, smem + 2 * 24576, 2, tid);

#pragma unroll 1
  for (int kt = 0; kt < NK; ++kt) {
    if (kt + 3 < NK) stage_tile(Ag, Bg, smem + ((kt + 3) & 3) * 24576, kt + 3, tid);
    int ahead = NK - 1 - kt;                  // staged tiles beyond kt
    if (ahead >= 3)      asm volatile("s_waitcnt vmcnt(9)" ::: "memory");
    else if (ahead == 2) asm volatile("s_waitcnt vmcnt(6)" ::: "memory");
    else if (ahead == 1) asm volatile("s_waitcnt vmcnt(3)" ::: "memory");
    else                 asm volatile("s_waitcnt vmcnt(0)" ::: "memory");
    __builtin_amdgcn_s_barrier();             // barrier#1: tile kt visible to all
    const char* buf = smem + (kt & 3) * 24576;
    bf16x8 af[4], bq[4];
#pragma unroll
    for (int i = 0; i < 4; i++) af[i] = *(const bf16x8*)(buf + aoff[i]);
#pragma unroll
    for (int j = 0; j < 4; j++) bq[j] = *(const bf16x8*)(buf + boff[j]);
    asm volatile("s_waitcnt lgkmcnt(0)" ::: "memory");
    __builtin_amdgcn_s_barrier();             // barrier#2: all reads of buf done
#pragma unroll
    for (int i = 0; i < 4; i++)
#pragma unroll
      for (int j = 0; j < 4; j++)
        acc[i][j] = MFMA_BF16(af[i], bq[j], acc[i][j]);
  }
}

__global__ __launch_bounds__(512) void k_gemm_qkv(const bf16* __restrict__ A,
                                                  const bf16* __restrict__ Bt,
                                                  const float* __restrict__ bias,
                                                  bf16* __restrict__ Qo,
                                                  bf16* __restrict__ Ko,
                                                  bf16* __restrict__ Vo) {
  const int NB = 12;                          // 3072 / 256
  int bm = blockIdx.x / NB, bn = blockIdx.x % NB;   // 64 x 12 = 768 blocks
  __shared__ __align__(16) char smem[98304];
  f32x4 acc[4][4] = {};
  gemm_core512(A, Bt, bm, bn, smem, acc);

  int tid = threadIdx.x, lane = tid & 63;
  int l15 = lane & 15, g = lane >> 4;
  int wid = tid >> 6, wr = wid >> 2, wc = wid & 3;
#pragma unroll
  for (int j = 0; j < 4; j++) {
    int n = bn * 256 + wc * 64 + j * 16 + l15;      // 0..3071
    float bj = bias[n];
    int which = n >> 10;                             // 0=Q 1=K 2=V
    int nn = n & 1023;
    int head = nn >> 6, d = nn & 63;
    bf16* dst = (which == 0) ? Qo : (which == 1) ? Ko : Vo;
#pragma unroll
    for (int i = 0; i < 4; i++) {
#pragma unroll
      for (int r = 0; r < 4; r++) {
        int row = bm * 128 + wr * 64 + i * 16 + g * 4 + r;
        int b = row >> 11, t = row & (SEQT - 1);
        dst[((size_t)(b * NHEADS + head) * SEQT + t) * 64 + d] =
            (bf16)(acc[i][j][r] + bj);
      }
    }
  }
}

__global__ __launch_bounds__(512) void k_gemm_out(const bf16* __restrict__ A,
                                                  const bf16* __restrict__ Bt,
                                                  const float* __restrict__ bias,
                                                  float* __restrict__ C) {
  const int NB = 4;                           // 1024 / 256
  int bm = blockIdx.x / NB, bn = blockIdx.x % NB;   // 64 x 4 = 256 blocks
  __shared__ __align__(16) char smem[98304];
  f32x4 acc[4][4] = {};
  gemm_core512(A, Bt, bm, bn, smem, acc);

  int tid = threadIdx.x, lane = tid & 63;
  int l15 = lane & 15, g = lane >> 4;
  int wid = tid >> 6, wr = wid >> 2, wc = wid & 3;
#pragma unroll
  for (int j = 0; j < 4; j++) {
    int n = bn * 256 + wc * 64 + j * 16 + l15;
    float bj = bias[n];
#pragma unroll
    for (int i = 0; i < 4; i++) {
#pragma unroll
      for (int r = 0; r < 4; r++) {
        int row = bm * 128 + wr * 64 + i * 16 + g * 4 + r;
        C[(size_t)row * DMODEL + n] = acc[i][j][r] + bj;
      }
    }
  }
}

// ---------------- flash attention (R7-measured kernel, verbatim) ----------
// Q,K: [BH][T][64] bf16 ; VT: [BH][64][T] bf16 ; out attn_o: [B*T][1024] bf16.
// Grid: (T/64)*BH = 2048 blocks x 128 threads (2 waves); longest-first.
// K+V double-buffered in LDS (32KB); measured 73.2us / MfmaUtil 24.7%.

__global__ __launch_bounds__(128) void k_attn(const bf16* __restrict__ Q,
                                              const bf16* __restrict__ Kg,
                                              const bf16* __restrict__ VT,
                                              bf16* __restrict__ Oo) {
  int bh = blockIdx.x & 63;
  int qi = 31 - (blockIdx.x >> 6);      // 64-row q-tile, longest-first, 0..31
  int tid = threadIdx.x, lane = tid & 63, wv = tid >> 6;   // wv 0..1
  int l31 = lane & 31, hi = lane >> 5;
  __shared__ __align__(16) char smem[32768];   // K dbuf 2x8K | V dbuf 2x8K

  const bf16* Qbh = Q + (size_t)bh * SEQT * 64;
  const char* Kbyte = (const char*)(Kg + (size_t)bh * SEQT * 64);
  const char* Vbyte = (const char*)(VT + (size_t)bh * 64 * SEQT);
  int qbase = qi * 64 + wv * 32;
  int ql = qbase + l31;                 // this lane's q row

  // staging: 8 chunks of 2KB (4 K + 4 V); 128 threads x 16B each
  int pp[4], lgK[4]; size_t vOff[4];
#pragma unroll
  for (int c = 0; c < 4; c++) {
    int p = c * 2048 + tid * 16;
    int row = p >> 7;
    int lg = p ^ ((row & 7) << 4);
    pp[c] = p; lgK[c] = lg;
    vOff[c] = (size_t)row * (SEQT * 2) + (lg & 127);
  }

  // Q fragments (B-operand): lane l holds Q[ql][d = s*16 + hi*8 + e]
  bf16x8 qf[4];
#pragma unroll
  for (int s = 0; s < 4; s++) {
    bf16x8 v = *(const bf16x8*)(Qbh + (size_t)ql * 64 + s * 16 + hi * 8);
#pragma unroll
    for (int e = 0; e < 8; e++) v[e] = (bf16)((float)v[e] * 0.125f);
    qf[s] = v;
  }

  // ones B-fragment for row-sum MFMA
  bf16x8 onesf;
#pragma unroll
  for (int e = 0; e < 8; e++) onesf[e] = (bf16)1.0f;

  float m = -INFINITY;
  f32x16 o0 = Z16, o1 = Z16, lacc = Z16;

  // prologue: stage tile 0 into buffer 0
#pragma unroll
  for (int c = 0; c < 4; c++) {
    gload_lds16(Kbyte + lgK[c], smem + pp[c]);
    gload_lds16(Vbyte + vOff[c], smem + 16384 + pp[c]);
  }

  int NT = qi + 1;
  for (int t = 0; t < NT; t++) {
    __syncthreads();                    // stage(t) landed; compute(t-1) done
    if (t + 1 < NT) {
      int nx = (t + 1) & 1;
      const char* kg = Kbyte + (size_t)(t + 1) * 8192;
      const char* vg = Vbyte + (size_t)(t + 1) * 128;
#pragma unroll
      for (int c = 0; c < 4; c++) {
        gload_lds16(kg + lgK[c], smem + nx * 8192 + pp[c]);
        gload_lds16(vg + vOff[c], smem + 16384 + nx * 8192 + pp[c]);
      }
    }
    const char* Ks = smem + (t & 1) * 8192;
    const char* Vs = smem + 16384 + (t & 1) * 8192;

    // ---- S^T halves: st[h] = K[32h..32h+31] @ Q^T ----
    f32x16 st[2];
    __builtin_amdgcn_s_setprio(1);
#pragma unroll
    for (int h = 0; h < 2; h++) {
      f32x16 acc = Z16;
#pragma unroll
      for (int s = 0; s < 4; s++) {
        int row = h * 32 + l31;
        bf16x8 kf = *(const bf16x8*)&Ks[(row * 128 + s * 32 + hi * 16) ^ ((l31 & 7) << 4)];
        acc = MFMA32(kf, qf[s], acc);
      }
      st[h] = acc;
    }
    __builtin_amdgcn_s_setprio(0);

    // ---- causal mask (last tile only) ----
    if (t == NT - 1) {
      int rel = ql - (t * 64 + 4 * hi);
#pragma unroll
      for (int r = 0; r < 16; r++) {
        const int R0 = (r & 3) + 8 * (r >> 2);
        if (R0 > rel) st[0][r] = -INFINITY;
        if (R0 > rel - 32) st[1][r] = -INFINITY;
      }
    }

    // ---- row max: 4 ILP chains + one cross shfl ----
    float m0 = -INFINITY, m1 = -INFINITY, m2 = -INFINITY, m3 = -INFINITY;
#pragma unroll
    for (int h = 0; h < 2; h++)
#pragma unroll
      for (int r = 0; r < 16; r += 4) {
        m0 = fmaxf(m0, st[h][r]);
        m1 = fmaxf(m1, st[h][r + 1]);
        m2 = fmaxf(m2, st[h][r + 2]);
        m3 = fmaxf(m3, st[h][r + 3]);
      }
    float mx = fmaxf(fmaxf(m0, m1), fmaxf(m2, m3));
    mx = fmaxf(mx, __shfl_xor(mx, 32));

    // ---- defer-max rescale (rare) ----
    if (__any(mx > m + 8.f)) {
      float mn = fmaxf(m, mx);
      float co = exp2v((m - mn) * LOG2E);
      m = mn;
#pragma unroll
      for (int r = 0; r < 16; r++) {
        const int R0 = (r & 3) + 8 * (r >> 2);
        float fac = __shfl(co, R0 + 4 * hi);
        o0[r] *= fac; o1[r] *= fac; lacc[r] *= fac;
      }
    }

    // ---- exp: p = 2^(s*log2e - m*log2e) ----
    float negmq = -m * LOG2E;
#pragma unroll
    for (int h = 0; h < 2; h++)
#pragma unroll
      for (int r = 0; r < 16; r++)
        st[h][r] = exp2v(fmaf(st[h][r], LOG2E, negmq));

    // ---- pack P -> A-frags, then PV + ones-sum ----
    __builtin_amdgcn_s_setprio(1);
#pragma unroll
    for (int h = 0; h < 2; h++) {
      unsigned pw[8];
#pragma unroll
      for (int i = 0; i < 8; i++) pw[i] = cvtpk_bf16(st[h][2 * i], st[h][2 * i + 1]);
      plswap(pw[0], pw[2]); plswap(pw[1], pw[3]);
      plswap(pw[4], pw[6]); plswap(pw[5], pw[7]);
      u32x4 f0 = {pw[0], pw[1], pw[2], pw[3]};
      u32x4 f1 = {pw[4], pw[5], pw[6], pw[7]};
      bf16x8 pa0 = __builtin_bit_cast(bf16x8, f0);   // kv slot 2h
      bf16x8 pa1 = __builtin_bit_cast(bf16x8, f1);   // kv slot 2h+1
      lacc = MFMA32(pa0, onesf, lacc);               // row sums, O-layout
      lacc = MFMA32(pa1, onesf, lacc);
      {
        int vrow = l31;
        bf16x8 bv0 = *(const bf16x8*)&Vs[(vrow * 128 + (2 * h) * 32 + hi * 16) ^ ((l31 & 7) << 4)];
        bf16x8 bv1 = *(const bf16x8*)&Vs[(vrow * 128 + (2 * h + 1) * 32 + hi * 16) ^ ((l31 & 7) << 4)];
        o0 = MFMA32(pa0, bv0, o0);
        o0 = MFMA32(pa1, bv1, o0);
      }
      {
        int vrow = 32 + l31;
        bf16x8 bv0 = *(const bf16x8*)&Vs[(vrow * 128 + (2 * h) * 32 + hi * 16) ^ ((l31 & 7) << 4)];
        bf16x8 bv1 = *(const bf16x8*)&Vs[(vrow * 128 + (2 * h + 1) * 32 + hi * 16) ^ ((l31 & 7) << 4)];
        o1 = MFMA32(pa0, bv0, o1);
        o1 = MFMA32(pa1, bv1, o1);
      }
    }
    __builtin_amdgcn_s_setprio(0);
  }

  // ---- normalize + write attn_out [B*T][1024] bf16 ----
  int b = bh >> 4, hd = bh & 15;
#pragma unroll
  for (int r = 0; r < 16; r++) {
    const int R0 = (r & 3) + 8 * (r >> 2);
    int qrow = qbase + R0 + 4 * hi;
    float inv = 1.f / lacc[r];
    size_t off = ((size_t)(b * SEQT + qrow)) * DMODEL + hd * 64;
    Oo[off + l31]      = (bf16)(o0[r] * inv);
    Oo[off + 32 + l31] = (bf16)(o1[r] * inv);
  }
}

// ---------------- launcher ----------------

extern "C" void kernel_launch(void* const* d_in, const int* in_sizes, int n_in,
                              void* d_out, int out_size, void* d_ws, size_t ws_size,
                              hipStream_t stream) {
  const float* x     = (const float*)d_in[0];
  const float* w_qkv = (const float*)d_in[1];
  const float* b_qkv = (const float*)d_in[2];
  const float* w_out = (const float*)d_in[3];
  const float* b_out = (const float*)d_in[4];
  float* out = (float*)d_out;

  char* ws = (char*)d_ws;
  bf16* xb    = (bf16*)(ws);                        // 16 MiB (reused as attn_out)
  bf16* wqkvT = (bf16*)(ws + (16u << 20));          //  6 MiB
  bf16* woutT = (bf16*)(ws + (22u << 20));          //  2 MiB
  bf16* Qb    = (bf16*)(ws + (24u << 20));          // 16 MiB
  bf16* Kb    = (bf16*)(ws + (40u << 20));          // 16 MiB
  bf16* Vb    = (bf16*)(ws + (56u << 20));          // 16 MiB
  bf16* VTb   = (bf16*)(ws + (72u << 20));          // 16 MiB (total 88 MiB)
  bf16* attn_o = xb;                                // xb dead after QKV GEMM

  k_cvt_f32_bf16<<<(MROWS * DMODEL / 8 + 255) / 256, 256, 0, stream>>>(x, xb, MROWS * DMODEL / 8);
  k_transpose_f32_bf16<<<16 * 48, 256, 0, stream>>>(w_qkv, wqkvT, DMODEL, 3 * DMODEL);
  k_transpose_f32_bf16<<<16 * 16, 256, 0, stream>>>(w_out, woutT, DMODEL, DMODEL);
  k_gemm_qkv<<<768, 512, 0, stream>>>(xb, wqkvT, b_qkv, Qb, Kb, Vb);
  k_transpose_v<<<64 * 32, 256, 0, stream>>>(Vb, VTb);
  k_attn<<<32 * 64, 128, 0, stream>>>(Qb, Kb, VTb, attn_o);
  k_gemm_out<<<256, 512, 0, stream>>>(attn_o, woutT, b_out, out);
}